// Round 1
// baseline (864.444 us; speedup 1.0000x reference)
//
#include <hip/hip_runtime.h>
#include <hip/hip_bf16.h>
#include <hip/hip_fp16.h>
#include <math.h>

#define N_NODES   100000
#define N_EDGES   1600000
#define D_FEAT    128
#define N_CLASSES 64

#define BKT_SHIFT 7                     // 128 nodes per bucket
#define BKT_NODES 128
#define NB        782                   // ceil(100000/128)
#define CAP       2560                  // per-bucket capacity (avg 2048)
#define CHUNK     8192                  // edges per bin block
#define NBLK_A    ((N_EDGES + CHUNK - 1) / CHUNK)   // 196
#define NBLK_G    ((N_NODES + 63) / 64)             // 1563

// ws layout (max extent 21,212,160 B):
//   deg    @ 0          (400,000 B)  per-node in-degree (no self loop)
//   bcnt   @ 400,384    (3,128 B)
//   binned @ 404,480    (8,007,680 B)
//   zp     @ 8,412,160  (12,800,000 B, fp16)
#define OFF_BCNT   400384
#define OFF_BINNED 404480
#define OFF_ZP     8412160

#define ACC_PITCH 66                    // fp32 pitch: 8B-aligned rows + bank spread

typedef __attribute__((ext_vector_type(8))) short bf16x8;
typedef __attribute__((ext_vector_type(4))) float f32x4;
typedef __attribute__((ext_vector_type(4))) unsigned int u32x4;

static __device__ inline unsigned f2bf1(float f) {
    unsigned u = __float_as_uint(f);
    return (u + 0x7FFF + ((u >> 16) & 1)) >> 16;     // RNE
}
static __device__ inline unsigned pack2(float a, float b) {
    return f2bf1(a) | (f2bf1(b) << 16);
}
static __device__ inline float2 h2f2(unsigned u) {
    __half2 h = *(__half2*)&u;
    return __half22float2(h);
}

// ---------------------------------------------------------------------------
// K1: bin edges into NB coarse buckets (contiguous per-block runs) + per-node
//     in-degree via global atomics. No per-node sort needed anymore.
// ---------------------------------------------------------------------------
__global__ __launch_bounds__(1024) void bin_kernel(const int* __restrict__ src,
                                                   const int* __restrict__ dst,
                                                   int* __restrict__ deg,
                                                   int* __restrict__ bcnt,
                                                   int* __restrict__ binned) {
    __shared__ int hist[NB];
    __shared__ int rbase[NB];
    __shared__ int dbuf[CHUNK];                // 32 KB
    const int tid = threadIdx.x;
    const int e0 = blockIdx.x * CHUNK;
    const int e1 = min(e0 + CHUNK, N_EDGES);
    const int n  = e1 - e0;

    for (int i = tid; i < NB; i += 1024) hist[i] = 0;
    __syncthreads();

    for (int i = tid; i < n; i += 1024) {
        int d = dst[e0 + i];
        dbuf[i] = d;
        atomicAdd(&hist[d >> BKT_SHIFT], 1);
        atomicAdd(&deg[d], 1);
    }
    __syncthreads();

    for (int i = tid; i < NB; i += 1024) {
        int h = hist[i];
        if (h) rbase[i] = atomicAdd(&bcnt[i], h);
        hist[i] = 0;                           // reuse as within-run cursor
    }
    __syncthreads();

    for (int i = tid; i < n; i += 1024) {
        int d = dbuf[i];
        int s = src[e0 + i];
        int bkt = d >> BKT_SHIFT;
        int pos = atomicAdd(&hist[bkt], 1);
        int off = rbase[bkt] + pos;
        if (off < CAP)                         // memory guard
            binned[bkt * CAP + off] = (s << BKT_SHIFT) | (d & (BKT_NODES - 1));
    }
}

// ---------------------------------------------------------------------------
// K2: zp[i][c] = rsqrt(indeg[i]+1) * (x @ W^T)[i][c]  via bf16 MFMA, fp16 out.
// ---------------------------------------------------------------------------
__global__ __launch_bounds__(256) void gemm_kernel(const float* __restrict__ x,
                                                   const float* __restrict__ W,
                                                   const int* __restrict__ deg,
                                                   __half* __restrict__ zp) {
    __shared__ short Xb[64 * 136];
    __shared__ short Wb[64 * 136];
    const int tid  = threadIdx.x;
    const int row0 = blockIdx.x * 64;

    const float4* __restrict__ W4 = (const float4*)W;
    for (int idx = tid; idx < 64 * 32; idx += 256) {
        int nn = idx >> 5, k4 = idx & 31;
        float4 v = W4[idx];
        uint2 p;
        p.x = pack2(v.x, v.y);
        p.y = pack2(v.z, v.w);
        *(uint2*)&Wb[nn * 136 + k4 * 4] = p;
    }
    const float4* __restrict__ x4 = (const float4*)x;
    for (int idx = tid; idx < 64 * 32; idx += 256) {
        int r = idx >> 5, k4 = idx & 31;
        int gr = min(row0 + r, N_NODES - 1);
        float4 v = x4[gr * 32 + k4];
        uint2 p;
        p.x = pack2(v.x, v.y);
        p.y = pack2(v.z, v.w);
        *(uint2*)&Xb[r * 136 + k4 * 4] = p;
    }
    __syncthreads();

    const int lane = tid & 63;
    const int wv   = tid >> 6;
    const int m    = lane & 15;
    const int half = lane >> 4;

    bf16x8 bfr[4][4];
#pragma unroll
    for (int t = 0; t < 4; t++)
#pragma unroll
        for (int j = 0; j < 4; j++)
            bfr[t][j] = *(bf16x8*)&Wb[(j * 16 + m) * 136 + t * 32 + half * 8];

    f32x4 acc[4];
#pragma unroll
    for (int j = 0; j < 4; j++) acc[j] = (f32x4){0.f, 0.f, 0.f, 0.f};

#pragma unroll
    for (int t = 0; t < 4; t++) {
        bf16x8 a = *(bf16x8*)&Xb[(wv * 16 + m) * 136 + t * 32 + half * 8];
#pragma unroll
        for (int j = 0; j < 4; j++)
            acc[j] = __builtin_amdgcn_mfma_f32_16x16x32_bf16(a, bfr[t][j], acc[j], 0, 0, 0);
    }

#pragma unroll
    for (int r = 0; r < 4; r++) {
        const int row = row0 + wv * 16 + half * 4 + r;
        if (row < N_NODES) {
            const int dg = deg[row];
            const float dinv = rsqrtf((float)(dg + 1));
#pragma unroll
            for (int j = 0; j < 4; j++)
                zp[row * N_CLASSES + j * 16 + m] = __float2half(acc[j][r] * dinv);
        }
    }
}

// ---------------------------------------------------------------------------
// K3: edge-centric aggregate + fused epilogue. One block per 128-node bucket.
//     acc[128][66] fp32 in LDS; 8 waves stream the bucket's edge list in
//     dense 64-edge batches: 8 independent 16B gathers in flight per wave
//     (fully unrolled slots, clamped addresses), ds_add_f32 accumulate.
//     Epilogue: self-loop + dinv + bias + log_softmax straight from LDS.
// ---------------------------------------------------------------------------
__global__ __launch_bounds__(512) void agg_kernel(const int* __restrict__ bcnt,
                                                  const int* __restrict__ binned,
                                                  const int* __restrict__ deg,
                                                  const __half* __restrict__ zp,
                                                  const float* __restrict__ b,
                                                  float* __restrict__ out) {
    __shared__ float acc[BKT_NODES * ACC_PITCH];   // 33,792 B

    const int tid  = threadIdx.x;
    const int bkt  = blockIdx.x;
    const int lane = tid & 63;
    const int wid  = tid >> 6;                 // 0..7
    const int sub  = lane >> 3;                // edge/node slot 0..7
    const int o8   = (lane & 7) * 8;           // class octet start

    for (int i = tid; i < BKT_NODES * ACC_PITCH; i += 512) acc[i] = 0.f;
    __syncthreads();

    const int n      = min(bcnt[bkt], CAP);
    const int base_g = bkt * CAP;

    for (int base = wid * 64; base < n; base += 8 * 64) {
        const int bn = min(n - base, 64);
        // one coalesced load -> 64 packed (src<<7 | nd) for this batch
        const int sidx = binned[base_g + base + min(lane, bn - 1)];

        int   rowv[8];
        u32x4 g[8];
#pragma unroll
        for (int j = 0; j < 8; j++)
            rowv[j] = __shfl(sidx, min(j * 8 + sub, bn - 1), 64);
#pragma unroll
        for (int j = 0; j < 8; j++)
            g[j] = *(const u32x4*)&zp[(rowv[j] >> BKT_SHIFT) * N_CLASSES + o8];
#pragma unroll
        for (int j = 0; j < 8; j++) {
            if (j * 8 + sub < bn) {
                const int nd = rowv[j] & (BKT_NODES - 1);
                float* ap = &acc[nd * ACC_PITCH + o8];
#pragma unroll
                for (int k = 0; k < 4; k++) {
                    float2 f = h2f2(g[j][k]);
                    atomicAdd(&ap[2 * k],     f.x);
                    atomicAdd(&ap[2 * k + 1], f.y);
                }
            }
        }
    }
    __syncthreads();

    // epilogue: 8 nodes per wave per pass, 2 passes cover 128 nodes
    for (int pass = 0; pass < 2; pass++) {
        const int nl   = pass * 64 + wid * 8 + sub;       // 0..127
        const int node = bkt * BKT_NODES + nl;
        if (node < N_NODES) {
            const u32x4 sg = *(const u32x4*)&zp[node * N_CLASSES + o8];
            const float2* ar = (const float2*)&acc[nl * ACC_PITCH + o8];
            const int dgn = deg[node];
            const float dinv = rsqrtf((float)(dgn + 1));

            float v[8];
#pragma unroll
            for (int k = 0; k < 4; k++) {
                float2 s  = h2f2(sg[k]);
                float2 av = ar[k];
                v[2 * k]     = (av.x + s.x) * dinv + b[o8 + 2 * k];
                v[2 * k + 1] = (av.y + s.y) * dinv + b[o8 + 2 * k + 1];
            }

            // max/sum over 8 local + the 8 octet lanes (masks 1,2,4 in-octet)
            float m = v[0];
#pragma unroll
            for (int k = 1; k < 8; k++) m = fmaxf(m, v[k]);
#pragma unroll
            for (int mask = 1; mask <= 4; mask <<= 1)
                m = fmaxf(m, __shfl_xor(m, mask, 64));
            float l = 0.f;
#pragma unroll
            for (int k = 0; k < 8; k++) l += __expf(v[k] - m);
#pragma unroll
            for (int mask = 1; mask <= 4; mask <<= 1)
                l += __shfl_xor(l, mask, 64);
            const float lg = m + __logf(l);

            float4 o0, o1;
            o0.x = v[0] - lg; o0.y = v[1] - lg; o0.z = v[2] - lg; o0.w = v[3] - lg;
            o1.x = v[4] - lg; o1.y = v[5] - lg; o1.z = v[6] - lg; o1.w = v[7] - lg;
            *(float4*)&out[node * N_CLASSES + o8]     = o0;
            *(float4*)&out[node * N_CLASSES + o8 + 4] = o1;
        }
    }
}

// ---------------------------------------------------------------------------
// Launch
// ---------------------------------------------------------------------------
extern "C" void kernel_launch(void* const* d_in, const int* in_sizes, int n_in,
                              void* d_out, int out_size, void* d_ws, size_t ws_size,
                              hipStream_t stream) {
    const float* x    = (const float*)d_in[0];
    const int*   edge = (const int*)d_in[1];   // [2,E]: src then dst
    const float* W    = (const float*)d_in[2];
    const float* b    = (const float*)d_in[3];
    float* out = (float*)d_out;

    char* ws = (char*)d_ws;
    int*    deg    = (int*)(ws);
    int*    bcnt   = (int*)(ws + OFF_BCNT);
    int*    binned = (int*)(ws + OFF_BINNED);
    __half* zp     = (__half*)(ws + OFF_ZP);

    const int* srcv = edge;
    const int* dstv = edge + N_EDGES;

    hipMemsetAsync(ws, 0, OFF_BINNED, stream);   // zero deg + bcnt
    bin_kernel<<<NBLK_A, 1024, 0, stream>>>(srcv, dstv, deg, bcnt, binned);
    gemm_kernel<<<NBLK_G, 256, 0, stream>>>(x, W, deg, zp);
    agg_kernel<<<NB, 512, 0, stream>>>(bcnt, binned, deg, zp, b, out);
}

// Round 2
// 193.867 us; speedup vs baseline: 4.4590x; 4.4590x over previous
//
#include <hip/hip_runtime.h>
#include <hip/hip_bf16.h>
#include <hip/hip_fp16.h>
#include <math.h>

#define N_NODES   100000
#define N_EDGES   1600000
#define D_FEAT    128
#define N_CLASSES 64

#define BKT_SHIFT 7                     // 128 nodes per bucket
#define BKT_NODES 128
#define NB        782                   // ceil(100000/128)
#define CAP       2560                  // per-bucket capacity (avg 2048)
#define CHUNK     8192                  // edges per bin block
#define NBLK_A    ((N_EDGES + CHUNK - 1) / CHUNK)   // 196
#define NBLK_G    ((N_NODES + 63) / 64)             // 1563

// ws layout (max extent 21,212,160 B — well under proven 34 MB):
//   meta   @ 0          (400,000 B)  start|(indeg<<21)
//   bcnt   @ 400,384    (3,128 B)
//   binned @ 404,480    (8,007,680 B)
//   zp     @ 8,412,160  (12,800,000 B, fp16)
#define OFF_BCNT   400384
#define OFF_BINNED 404480
#define OFF_ZP     8412160

typedef __attribute__((ext_vector_type(8))) short bf16x8;
typedef __attribute__((ext_vector_type(4))) float f32x4;
typedef __attribute__((ext_vector_type(4))) unsigned int u32x4;

static __device__ inline unsigned f2bf1(float f) {
    unsigned u = __float_as_uint(f);
    return (u + 0x7FFF + ((u >> 16) & 1)) >> 16;     // RNE
}
static __device__ inline unsigned pack2(float a, float b) {
    return f2bf1(a) | (f2bf1(b) << 16);
}
static __device__ inline float2 h2f2(unsigned u) {
    __half2 h = *(__half2*)&u;
    return __half22float2(h);
}

// ---------------------------------------------------------------------------
// K1: bin edges into NB coarse buckets (contiguous per-block runs).
//     Single pass over dst: stage into LDS during histogram, scatter from LDS.
// ---------------------------------------------------------------------------
__global__ __launch_bounds__(1024) void bin_kernel(const int* __restrict__ src,
                                                   const int* __restrict__ dst,
                                                   int* __restrict__ bcnt,
                                                   int* __restrict__ binned) {
    __shared__ int hist[NB];
    __shared__ int rbase[NB];
    __shared__ int dbuf[CHUNK];                // 32 KB
    const int tid = threadIdx.x;
    const int e0 = blockIdx.x * CHUNK;
    const int e1 = min(e0 + CHUNK, N_EDGES);
    const int n  = e1 - e0;

    for (int i = tid; i < NB; i += 1024) hist[i] = 0;
    __syncthreads();

    for (int i = tid; i < n; i += 1024) {
        int d = dst[e0 + i];
        dbuf[i] = d;
        atomicAdd(&hist[d >> BKT_SHIFT], 1);
    }
    __syncthreads();

    for (int i = tid; i < NB; i += 1024) {
        int h = hist[i];
        if (h) rbase[i] = atomicAdd(&bcnt[i], h);
        hist[i] = 0;                           // reuse as within-run cursor
    }
    __syncthreads();

    for (int i = tid; i < n; i += 1024) {
        int d = dbuf[i];
        int s = src[e0 + i];
        int bkt = d >> BKT_SHIFT;
        int pos = atomicAdd(&hist[bkt], 1);
        int off = rbase[bkt] + pos;
        if (off < CAP)                         // memory guard
            binned[bkt * CAP + off] = (s << BKT_SHIFT) | (d & (BKT_NODES - 1));
    }
}

// ---------------------------------------------------------------------------
// K2: per-bucket in-place sort-by-node + degree metadata.
// ---------------------------------------------------------------------------
__global__ __launch_bounds__(1024) void sortdeg_kernel(const int* __restrict__ bcnt,
                                                       int* __restrict__ binned,
                                                       int* __restrict__ meta) {
    __shared__ int buf[CAP];
    __shared__ int hcnt[BKT_NODES];
    __shared__ int cur[BKT_NODES];
    __shared__ int rowstart[BKT_NODES + 1];

    const int tid  = threadIdx.x;
    const int lane = tid & 63;
    const int wid  = tid >> 6;

    if (tid < BKT_NODES) { hcnt[tid] = 0; cur[tid] = 0; }
    __syncthreads();

    const int n    = min(bcnt[blockIdx.x], CAP);
    const int base = blockIdx.x * CAP;

    for (int i = tid; i < n; i += 1024) {
        int v = binned[base + i];
        buf[i] = v;
        atomicAdd(&hcnt[v & (BKT_NODES - 1)], 1);
    }
    __syncthreads();

    if (wid == 0) {
        int v0 = hcnt[lane];
        int v1 = hcnt[64 + lane];
        int s0 = v0;
#pragma unroll
        for (int off = 1; off < 64; off <<= 1) {
            int t = __shfl_up(s0, off, 64);
            if (lane >= off) s0 += t;
        }
        int tot0 = __shfl(s0, 63, 64);
        int s1 = v1;
#pragma unroll
        for (int off = 1; off < 64; off <<= 1) {
            int t = __shfl_up(s1, off, 64);
            if (lane >= off) s1 += t;
        }
        s1 += tot0;
        if (lane == 0) rowstart[0] = 0;
        rowstart[1 + lane]  = s0;
        rowstart[65 + lane] = s1;
    }
    __syncthreads();

    for (int i = tid; i < n; i += 1024) {
        int v  = buf[i];
        int nd = v & (BKT_NODES - 1);
        int p  = atomicAdd(&cur[nd], 1);
        binned[base + rowstart[nd] + p] = v >> BKT_SHIFT;
    }

    if (tid < BKT_NODES) {
        int node = blockIdx.x * BKT_NODES + tid;
        if (node < N_NODES) {
            int st = base + rowstart[tid];
            int dg = min(hcnt[tid], 2047);
            meta[node] = st | (dg << 21);
        }
    }
}

// ---------------------------------------------------------------------------
// K3: zp[i][c] = rsqrt(indeg[i]+1) * (x @ W^T)[i][c]  via bf16 MFMA, fp16 out.
// ---------------------------------------------------------------------------
__global__ __launch_bounds__(256) void gemm_kernel(const float* __restrict__ x,
                                                   const float* __restrict__ W,
                                                   const int* __restrict__ meta,
                                                   __half* __restrict__ zp) {
    __shared__ short Xb[64 * 136];
    __shared__ short Wb[64 * 136];
    const int tid  = threadIdx.x;
    const int row0 = blockIdx.x * 64;

    const float4* __restrict__ W4 = (const float4*)W;
    for (int idx = tid; idx < 64 * 32; idx += 256) {
        int nn = idx >> 5, k4 = idx & 31;
        float4 v = W4[idx];
        uint2 p;
        p.x = pack2(v.x, v.y);
        p.y = pack2(v.z, v.w);
        *(uint2*)&Wb[nn * 136 + k4 * 4] = p;
    }
    const float4* __restrict__ x4 = (const float4*)x;
    for (int idx = tid; idx < 64 * 32; idx += 256) {
        int r = idx >> 5, k4 = idx & 31;
        int gr = min(row0 + r, N_NODES - 1);
        float4 v = x4[gr * 32 + k4];
        uint2 p;
        p.x = pack2(v.x, v.y);
        p.y = pack2(v.z, v.w);
        *(uint2*)&Xb[r * 136 + k4 * 4] = p;
    }
    __syncthreads();

    const int lane = tid & 63;
    const int wv   = tid >> 6;
    const int m    = lane & 15;
    const int half = lane >> 4;

    bf16x8 bfr[4][4];
#pragma unroll
    for (int t = 0; t < 4; t++)
#pragma unroll
        for (int j = 0; j < 4; j++)
            bfr[t][j] = *(bf16x8*)&Wb[(j * 16 + m) * 136 + t * 32 + half * 8];

    f32x4 acc[4];
#pragma unroll
    for (int j = 0; j < 4; j++) acc[j] = (f32x4){0.f, 0.f, 0.f, 0.f};

#pragma unroll
    for (int t = 0; t < 4; t++) {
        bf16x8 a = *(bf16x8*)&Xb[(wv * 16 + m) * 136 + t * 32 + half * 8];
#pragma unroll
        for (int j = 0; j < 4; j++)
            acc[j] = __builtin_amdgcn_mfma_f32_16x16x32_bf16(a, bfr[t][j], acc[j], 0, 0, 0);
    }

#pragma unroll
    for (int r = 0; r < 4; r++) {
        const int row = row0 + wv * 16 + half * 4 + r;
        if (row < N_NODES) {
            const int dg = ((unsigned)meta[row]) >> 21;
            const float dinv = rsqrtf((float)(dg + 1));
#pragma unroll
            for (int j = 0; j < 4; j++)
                zp[row * N_CLASSES + j * 16 + m] = __float2half(acc[j][r] * dinv);
        }
    }
}

// ---------------------------------------------------------------------------
// K4: gather-accumulate + fused epilogue. One wave per node.
//     Change vs round-0: the per-batch gather loop is a COMPILE-TIME 8-slot
//     unroll with clamped indices -> 8 independent 16B gathers in flight
//     (was a runtime jm-bounded loop = 1 in flight). Clamped duplicates hit
//     the just-fetched zp row in L1. Self-loop gather hoisted to overlap.
//     Accumulation stays in registers (LDS fp32 atomics proven pathological).
// ---------------------------------------------------------------------------
__global__ __launch_bounds__(256) void agg_kernel(const int* __restrict__ meta,
                                                  const int* __restrict__ binned,
                                                  const __half* __restrict__ zp,
                                                  const float* __restrict__ b,
                                                  float* __restrict__ out) {
    const int node = blockIdx.x * 4 + (threadIdx.x >> 6);
    const int lane = threadIdx.x & 63;
    const int sub  = lane >> 3;                 // edge slot 0..7
    const int o8   = (lane & 7) * 8;            // class octet start

    const unsigned mv = (unsigned)meta[node];
    const int start = mv & 0x1FFFFF;
    const int cnt   = mv >> 21;

    // self-loop gather issued before the edge loop (overlaps edge latency)
    const u32x4 sg = *(const u32x4*)&zp[node * N_CLASSES + o8];

    float a[8] = {0.f, 0.f, 0.f, 0.f, 0.f, 0.f, 0.f, 0.f};
    for (int base = 0; base < cnt; base += 64) {
        const int bn = min(cnt - base, 64);
        // one load -> 64 indices for this batch
        const int sidx = binned[start + base + min(lane, bn - 1)];

        int rowv[8];
#pragma unroll
        for (int j = 0; j < 8; j++)
            rowv[j] = __shfl(sidx, min(j * 8 + sub, bn - 1), 64);

        u32x4 g[8];
#pragma unroll
        for (int j = 0; j < 8; j++)
            g[j] = *(const u32x4*)&zp[rowv[j] * N_CLASSES + o8];

#pragma unroll
        for (int j = 0; j < 8; j++) {
            if (j * 8 + sub < bn) {
#pragma unroll
                for (int k = 0; k < 4; k++) {
                    float2 f = h2f2(g[j][k]);
                    a[2 * k]     += f.x;
                    a[2 * k + 1] += f.y;
                }
            }
        }
    }
    // combine the 8 edge slots (xor 8,16,32): each octet-lane ends with full sums
#pragma unroll
    for (int mask = 8; mask <= 32; mask <<= 1)
#pragma unroll
        for (int k = 0; k < 8; k++)
            a[k] += __shfl_xor(a[k], mask, 64);

    // self-loop
#pragma unroll
    for (int k = 0; k < 4; k++) {
        float2 f = h2f2(sg[k]);
        a[2 * k]     += f.x;
        a[2 * k + 1] += f.y;
    }

    const float dinv = rsqrtf((float)(cnt + 1));
    float v[8];
#pragma unroll
    for (int k = 0; k < 8; k++) v[k] = a[k] * dinv + b[o8 + k];

    // max/sum over 8 local + the 8 octet lanes (masks 1,2,4 stay in-octet)
    float m = v[0];
#pragma unroll
    for (int k = 1; k < 8; k++) m = fmaxf(m, v[k]);
#pragma unroll
    for (int mask = 1; mask <= 4; mask <<= 1)
        m = fmaxf(m, __shfl_xor(m, mask, 64));
    float l = 0.f;
#pragma unroll
    for (int k = 0; k < 8; k++) l += __expf(v[k] - m);
#pragma unroll
    for (int mask = 1; mask <= 4; mask <<= 1)
        l += __shfl_xor(l, mask, 64);
    const float lg = m + __logf(l);

    if (sub == 0) {
        float4 o0, o1;
        o0.x = v[0] - lg; o0.y = v[1] - lg; o0.z = v[2] - lg; o0.w = v[3] - lg;
        o1.x = v[4] - lg; o1.y = v[5] - lg; o1.z = v[6] - lg; o1.w = v[7] - lg;
        *(float4*)&out[node * N_CLASSES + o8]     = o0;
        *(float4*)&out[node * N_CLASSES + o8 + 4] = o1;
    }
}

// ---------------------------------------------------------------------------
// Launch
// ---------------------------------------------------------------------------
extern "C" void kernel_launch(void* const* d_in, const int* in_sizes, int n_in,
                              void* d_out, int out_size, void* d_ws, size_t ws_size,
                              hipStream_t stream) {
    const float* x    = (const float*)d_in[0];
    const int*   edge = (const int*)d_in[1];   // [2,E]: src then dst
    const float* W    = (const float*)d_in[2];
    const float* b    = (const float*)d_in[3];
    float* out = (float*)d_out;

    char* ws = (char*)d_ws;
    int*    meta   = (int*)(ws);
    int*    bcnt   = (int*)(ws + OFF_BCNT);
    int*    binned = (int*)(ws + OFF_BINNED);
    __half* zp     = (__half*)(ws + OFF_ZP);

    const int* srcv = edge;
    const int* dstv = edge + N_EDGES;

    hipMemsetAsync(bcnt, 0, NB * sizeof(int), stream);
    bin_kernel<<<NBLK_A, 1024, 0, stream>>>(srcv, dstv, bcnt, binned);
    sortdeg_kernel<<<NB, 1024, 0, stream>>>(bcnt, binned, meta);
    gemm_kernel<<<NBLK_G, 256, 0, stream>>>(x, W, meta, zp);
    agg_kernel<<<N_NODES / 4, 256, 0, stream>>>(meta, binned, zp, b, out);
}